// Round 1
// 250.794 us; speedup vs baseline: 1.0632x; 1.0632x over previous
//
#include <hip/hip_runtime.h>

namespace {

constexpr int kE  = 1024;
constexpr int kH  = 16;
constexpr int kR  = 256;
constexpr int kHD = 64;
constexpr int kB  = 2;
constexpr int kS  = 2048;
constexpr int kM  = kB * kS;   // 4096

typedef float  floatx4 __attribute__((ext_vector_type(4)));
typedef short  short8  __attribute__((ext_vector_type(8)));
typedef short  short4  __attribute__((ext_vector_type(4)));
typedef unsigned int uint2v __attribute__((ext_vector_type(2)));

__device__ inline short f2bf(float f) {
  union { float f; unsigned u; } x{f};
  unsigned r = x.u + 0x7FFF + ((x.u >> 16) & 1);   // RNE
  return (short)(r >> 16);
}

// packed f32x2 -> bf16x2 (RNE), one VALU instruction on gfx950
__device__ inline unsigned cvt_pk_bf16(float a, float b) {
#if defined(__HIP_DEVICE_COMPILE__)
  unsigned r;
  asm("v_cvt_pk_bf16_f32 %0, %1, %2" : "=v"(r) : "v"(a), "v"(b));
  return r;
#else
  return (unsigned)(unsigned short)f2bf(a) | ((unsigned)(unsigned short)f2bf(b) << 16);
#endif
}

__device__ inline short4 pack2(unsigned a, unsigned b) {
  union { uint2v u; short4 s; } x;
  x.u[0] = a; x.u[1] = b;
  return x.s;
}

// raw v_exp_f32 (2^x) — softmax runs in log2 domain (log2e folded into Q scale)
__device__ inline float fexp2(float x) {
#if defined(__HIP_DEVICE_COMPILE__) && __has_builtin(__builtin_amdgcn_exp2f)
  return __builtin_amdgcn_exp2f(x);
#else
  return exp2f(x);
#endif
}

// async global->LDS, 16B per lane. LDS dest = wave-uniform base + lane*16.
__device__ inline void async_copy16(const void* g, void* l) {
  __builtin_amdgcn_global_load_lds(
      (const __attribute__((address_space(1))) unsigned int*)g,
      (__attribute__((address_space(3))) unsigned int*)l,
      16, 0, 0);
}

// 16x16x16 bf16 MFMA (A/B = 4 bf16 in 2 VGPRs). __has_builtin is FALSE on the
// host pass of the HIP TU -> must guard with __HIP_DEVICE_COMPILE__ and give
// the host a parse-only stub (device pass verified working in round 3).
#if defined(__HIP_DEVICE_COMPILE__)
  #if __has_builtin(__builtin_amdgcn_mfma_f32_16x16x16bf16_1k)
    #define MFMA16(a, b, c) __builtin_amdgcn_mfma_f32_16x16x16bf16_1k(a, b, c, 0, 0, 0)
  #elif __has_builtin(__builtin_amdgcn_mfma_f32_16x16x16_bf16)
    #define MFMA16(a, b, c) __builtin_amdgcn_mfma_f32_16x16x16_bf16(a, b, c, 0, 0, 0)
  #else
    #error "no 16x16x16 bf16 MFMA builtin on device"
  #endif
#else
  #define MFMA16(a, b, c) (c)   // host pass: never executed
#endif

// ---------------------------------------------------------------------------
// Weight prep: fp32 W (K,N) row-major -> bf16 W^T (N,K) row-major.
// ---------------------------------------------------------------------------
struct PrepArgs { const float* src[8]; short* dst[8]; };

__global__ __launch_bounds__(256) void prep_weights(PrepArgs pa) {
  const int id = blockIdx.y;
  const bool lo = (id & 1) == 0;
  const int K = lo ? 1024 : 256;
  const int N = lo ? 256 : 1024;
  const int tiles_k = K >> 6;
  const int k0 = (blockIdx.x % tiles_k) * 64;
  const int n0 = (blockIdx.x / tiles_k) * 64;
  const float* src = pa.src[id];
  short* dst = pa.dst[id];

  __shared__ float tile[64][68];
  const int t  = threadIdx.x;
  const int c4 = (t & 15) * 4;
  const int r  = t >> 4;

#pragma unroll
  for (int i = 0; i < 4; ++i) {
    const int rk = r + i * 16;
    *(float4*)&tile[rk][c4] = *(const float4*)&src[(size_t)(k0 + rk) * N + n0 + c4];
  }
  __syncthreads();
#pragma unroll
  for (int i = 0; i < 4; ++i) {
    const int rn = r + i * 16;
    short4 o = { f2bf(tile[c4 + 0][rn]), f2bf(tile[c4 + 1][rn]),
                 f2bf(tile[c4 + 2][rn]), f2bf(tile[c4 + 3][rn]) };
    *(short4*)&dst[(size_t)(n0 + rn) * K + k0 + c4] = o;
  }
}

// ---------------------------------------------------------------------------
// q/k/v fp32 -> bf16 row-major. 8 elements per thread.
// ---------------------------------------------------------------------------
__global__ __launch_bounds__(256) void convert_in(
    const float* q, const float* k, const float* v,
    short* xq, short* xk, short* xv)
{
  const float* srcs[3] = {q, k, v};
  short* dsts[3] = {xq, xk, xv};
  const float* s = srcs[blockIdx.y];
  short* d = dsts[blockIdx.y];
  const size_t i = ((size_t)blockIdx.x * 256 + threadIdx.x) * 8;
  float4 a = *(const float4*)(s + i);
  float4 b = *(const float4*)(s + i + 4);
  short8 o = { f2bf(a.x), f2bf(a.y), f2bf(a.z), f2bf(a.w),
               f2bf(b.x), f2bf(b.y), f2bf(b.z), f2bf(b.w) };
  *(short8*)(d + i) = o;
}

// ---------------------------------------------------------------------------
// bf16 MFMA GEMM, NT form: C[M,N] = A[M,K] @ Bt[N,K]^T + bias, M=4096.
// MODE 0: bf16 row-major out.
// MODE 1: bf16 out in attention layouts: z<2 -> head-major (b*H+h, s, d);
//         z==2 -> head-major transposed (b*H+h, d, s).
// MODE 2: fp32 row-major out.
// ---------------------------------------------------------------------------
struct GemmArgs {
  const short* A[3]; const short* Bt[3]; const float* bias[3];
  void* C[3]; float scale[3];
};

template <int N, int K, int BM, int BN, int MODE>
__global__ __launch_bounds__(256) void gemm_bf16(GemmArgs args) {
  constexpr int TILES_N = N / BN;
  constexpr int WTM = BM / 2, WTN = BN / 2;
  constexpr int FI = WTM / 16, FJ = WTN / 16;
  constexpr int AROUNDS = (BM * 64) / 4096;
  constexpr int BROUNDS = (BN * 64) / 4096;

  const int z = blockIdx.y;
  const int row0 = (blockIdx.x / TILES_N) * BM;
  const int col0 = (blockIdx.x % TILES_N) * BN;
  const short* A  = args.A[z];
  const short* Bt = args.Bt[z];
  const float* bias = args.bias[z];
  const float scale = args.scale[z];

  __shared__ short As[BM * 32];
  __shared__ short Bs[BN * 32];

  const int t    = threadIdx.x;
  const int wave = t >> 6;
  const int lane = t & 63;
  const int lq   = lane & 15;
  const int quad = lane >> 4;
  const int wm0  = (wave >> 1) * WTM;
  const int wn0  = (wave & 1) * WTN;

  const int srow = t >> 2;
  const int scol = (t & 3) * 8;

  floatx4 acc[FI][FJ] = {};

  for (int kk = 0; kk < K; kk += 32) {
#pragma unroll
    for (int r = 0; r < AROUNDS; ++r)
      async_copy16(A + (size_t)(row0 + r * 64 + srow) * K + kk + scol,
                   (char*)As + r * 4096 + wave * 1024);
#pragma unroll
    for (int r = 0; r < BROUNDS; ++r)
      async_copy16(Bt + (size_t)(col0 + r * 64 + srow) * K + kk + scol,
                   (char*)Bs + r * 4096 + wave * 1024);
    __syncthreads();

    short8 af[FI], bf[FJ];
#pragma unroll
    for (int i = 0; i < FI; ++i)
      af[i] = *(const short8*)((const char*)As + ((wm0 + i * 16 + lq) * 64 + quad * 16));
#pragma unroll
    for (int j = 0; j < FJ; ++j)
      bf[j] = *(const short8*)((const char*)Bs + ((wn0 + j * 16 + lq) * 64 + quad * 16));
#pragma unroll
    for (int i = 0; i < FI; ++i)
#pragma unroll
      for (int j = 0; j < FJ; ++j)
        acc[i][j] = __builtin_amdgcn_mfma_f32_16x16x32_bf16(af[i], bf[j], acc[i][j], 0, 0, 0);
    __syncthreads();
  }

#pragma unroll
  for (int i = 0; i < FI; ++i) {
    const int rbase = row0 + wm0 + i * 16 + quad * 4;
#pragma unroll
    for (int j = 0; j < FJ; ++j) {
      const int col = col0 + wn0 + j * 16 + lq;
      const float bj = bias[col];
      if (MODE == 2) {
        float* C = (float*)args.C[z];
#pragma unroll
        for (int r = 0; r < 4; ++r)
          C[(size_t)(rbase + r) * N + col] = (acc[i][j][r] + bj) * scale;
      } else if (MODE == 1) {
        short* C = (short*)args.C[z];
        const int h = col >> 6, d = col & 63;
        const int b = rbase >> 11, s = rbase & 2047;
        if (z == 2) {
          // V^T head-major: (bh, d, s); 4 consecutive s
          short4 o = { f2bf(acc[i][j][0] + bj), f2bf(acc[i][j][1] + bj),
                       f2bf(acc[i][j][2] + bj), f2bf(acc[i][j][3] + bj) };
          *(short4*)&C[((size_t)((b * 16 + h) * 64 + d)) * 2048 + s] = o;
        } else {
          // Q/K head-major: (bh, s, d)
#pragma unroll
          for (int r = 0; r < 4; ++r)
            C[((size_t)((b * 16 + h) * 2048 + s + r)) * 64 + d] =
                f2bf((acc[i][j][r] + bj) * scale);
        }
      } else {
        short* C = (short*)args.C[z];
#pragma unroll
        for (int r = 0; r < 4; ++r)
          C[(size_t)(rbase + r) * N + col] = f2bf((acc[i][j][r] + bj) * scale);
      }
    }
  }
}

// ---------------------------------------------------------------------------
// Flash attention, bf16 MFMA, log2-domain softmax.
// Block = 4 waves, 128 q-rows (32/wave as 2 q-tiles). Per 64-key chunk:
// K (64x64) and V^T (64x64) staged ONCE into padded LDS; the K/V LDS
// fragments are reused across both q-tiles (halves LDS+staging per q).
// S^T = K @ Q^T; P stays in registers; O^T += V^T @ P^T.
// Softmax diet: exp2 (log2e pre-folded into Q scale), v_cvt_pk_bf16_f32 for
// P->bf16, defer-max (skip rescale while chunk max <= m + 10 in log2 units).
// ---------------------------------------------------------------------------
__global__ __launch_bounds__(256) void attn_mfma(
    const short* __restrict__ Qp, const short* __restrict__ Kp,
    const short* __restrict__ Vtp, short* __restrict__ O)
{
  __shared__ short Ks[64][72];   // [local key][d], pad 72 (144B rows, 16B-aligned)
  __shared__ short Vs[64][72];   // [d][local key]

  const int t    = threadIdx.x;
  const int wave = t >> 6;
  const int lane = t & 63;
  const int lq   = lane & 15;
  const int quad = lane >> 4;

  const int q0 = blockIdx.x * 128;
  const int bh = blockIdx.y;
  const int b  = bh >> 4;
  const int h  = bh & 15;

  // Q fragments (head-major (bh,s,d)): n=q=lq, k=d. Two q-tiles per wave.
  short8 qf0[2], qf1[2];
#pragma unroll
  for (int qt = 0; qt < 2; ++qt) {
    const short* qrow = Qp + ((size_t)bh * kS + q0 + wave * 32 + qt * 16 + lq) * 64;
    qf0[qt] = *(const short8*)(qrow + quad * 8);
    qf1[qt] = *(const short8*)(qrow + 32 + quad * 8);
  }

  const short* Kbase = Kp  + (size_t)bh * kS * 64;   // (s, d) rows of 128B
  const short* Vbase = Vtp + (size_t)bh * 64 * kS;   // (d, s) rows of 4KB

  // staging: wave w covers rows w*16 .. w*16+15 via two 8-row coalesced loads
  const int srow = wave * 16 + (lane >> 3);
  const int scol = (lane & 7) * 8;

  floatx4 Oacc[4][2] = {};
  float m[2] = {-1e30f, -1e30f};
  float l[2] = {0.f, 0.f};

  short8 gk0 = *(const short8*)(Kbase + (size_t)(srow) * 64 + scol);
  short8 gk1 = *(const short8*)(Kbase + (size_t)(srow + 8) * 64 + scol);
  short8 gv0 = *(const short8*)(Vbase + (size_t)srow * kS + scol);
  short8 gv1 = *(const short8*)(Vbase + (size_t)(srow + 8) * kS + scol);

  for (int kc = 0; kc < kS; kc += 64) {
    __syncthreads();                      // previous chunk's reads done
    *(short8*)&Ks[srow][scol]     = gk0;
    *(short8*)&Ks[srow + 8][scol] = gk1;
    *(short8*)&Vs[srow][scol]     = gv0;
    *(short8*)&Vs[srow + 8][scol] = gv1;
    __syncthreads();                      // tiles visible

    if (kc + 64 < kS) {                   // prefetch next chunk (hidden by compute)
      gk0 = *(const short8*)(Kbase + (size_t)(kc + 64 + srow) * 64 + scol);
      gk1 = *(const short8*)(Kbase + (size_t)(kc + 64 + srow + 8) * 64 + scol);
      gv0 = *(const short8*)(Vbase + (size_t)srow * kS + kc + 64 + scol);
      gv1 = *(const short8*)(Vbase + (size_t)(srow + 8) * kS + kc + 64 + scol);
    }

    // ---- scores: S^T tiles (key16 x q16), A = K rows from LDS (shared by qt) ----
    floatx4 Sc[4][2];
#pragma unroll
    for (int tt = 0; tt < 4; ++tt) {
      short8 a0 = *(const short8*)&Ks[tt * 16 + lq][quad * 8];
      short8 a1 = *(const short8*)&Ks[tt * 16 + lq][32 + quad * 8];
#pragma unroll
      for (int qt = 0; qt < 2; ++qt) {
        floatx4 c = {};
        c = __builtin_amdgcn_mfma_f32_16x16x32_bf16(a0, qf0[qt], c, 0, 0, 0);
        c = __builtin_amdgcn_mfma_f32_16x16x32_bf16(a1, qf1[qt], c, 0, 0, 0);
        Sc[tt][qt] = c;
      }
    }

    // ---- online softmax (log2 domain), per q-tile ----
    short4 pf[4][2];
#pragma unroll
    for (int qt = 0; qt < 2; ++qt) {
      float x0 = fmaxf(fmaxf(Sc[0][qt][0], Sc[0][qt][1]), fmaxf(Sc[0][qt][2], Sc[0][qt][3]));
      float x1 = fmaxf(fmaxf(Sc[1][qt][0], Sc[1][qt][1]), fmaxf(Sc[1][qt][2], Sc[1][qt][3]));
      float x2 = fmaxf(fmaxf(Sc[2][qt][0], Sc[2][qt][1]), fmaxf(Sc[2][qt][2], Sc[2][qt][3]));
      float x3 = fmaxf(fmaxf(Sc[3][qt][0], Sc[3][qt][1]), fmaxf(Sc[3][qt][2], Sc[3][qt][3]));
      float plane = fmaxf(fmaxf(x0, x1), fmaxf(x2, x3));

      // defer-max: only rescale when this chunk's max grew past m+10 (log2);
      // otherwise P is bounded by 2^10 which fp32 accum / bf16 handle fine.
      if (!__all(plane <= m[qt] + 10.f)) {
        float mc = fmaxf(plane, __shfl_xor(plane, 16, 64));
        mc = fmaxf(mc, __shfl_xor(mc, 32, 64));
        const float mn = fmaxf(m[qt], mc);
        const float a = fexp2(m[qt] - mn);
        m[qt] = mn;
        l[qt] *= a;
#pragma unroll
        for (int dt = 0; dt < 4; ++dt) Oacc[dt][qt] *= a;
      }

      float ls = 0.f;
#pragma unroll
      for (int tt = 0; tt < 4; ++tt) {
        float p0 = fexp2(Sc[tt][qt][0] - m[qt]);
        float p1 = fexp2(Sc[tt][qt][1] - m[qt]);
        float p2 = fexp2(Sc[tt][qt][2] - m[qt]);
        float p3 = fexp2(Sc[tt][qt][3] - m[qt]);
        ls += (p0 + p1) + (p2 + p3);
        pf[tt][qt] = pack2(cvt_pk_bf16(p0, p1), cvt_pk_bf16(p2, p3));
      }
      l[qt] += ls;
    }

    // ---- PV: O^T += V^T @ P^T, A = V^T rows from LDS (shared by qt) ----
#pragma unroll
    for (int dt = 0; dt < 4; ++dt) {
#pragma unroll
      for (int tt = 0; tt < 4; ++tt) {
        short4 vf = *(const short4*)&Vs[dt * 16 + lq][tt * 16 + quad * 4];
#pragma unroll
        for (int qt = 0; qt < 2; ++qt)
          Oacc[dt][qt] = MFMA16(vf, pf[tt][qt], Oacc[dt][qt]);
      }
    }
  }

  // ---- epilogue ----
#pragma unroll
  for (int qt = 0; qt < 2; ++qt) {
    float lv = l[qt];
    lv += __shfl_xor(lv, 16, 64);
    lv += __shfl_xor(lv, 32, 64);
    const float inv = 1.f / lv;

    short* orow = O + ((size_t)(b * kS + q0 + wave * 32 + qt * 16 + lq)) * kE + h * kHD;
#pragma unroll
    for (int dt = 0; dt < 4; ++dt) {
      short4 o = pack2(cvt_pk_bf16(Oacc[dt][qt][0] * inv, Oacc[dt][qt][1] * inv),
                       cvt_pk_bf16(Oacc[dt][qt][2] * inv, Oacc[dt][qt][3] * inv));
      *(short4*)&orow[dt * 16 + quad * 4] = o;
    }
  }
}

}  // namespace

extern "C" void kernel_launch(void* const* d_in, const int* in_sizes, int n_in,
                              void* d_out, int out_size, void* d_ws, size_t ws_size,
                              hipStream_t stream) {
  // ---- workspace layout (bf16 shorts) ----
  short* ws = (short*)d_ws;
  short* Xq  = ws;                         // 4M
  short* Xk  = Xq  + (size_t)kM * kE;
  short* Xv  = Xk  + (size_t)kM * kE;
  short* Tq  = Xv  + (size_t)kM * kE;      // 1M each
  short* Tk  = Tq  + (size_t)kM * kR;
  short* Tv  = Tk  + (size_t)kM * kR;
  short* Qh  = Tv  + (size_t)kM * kR;      // 4M each; head-major layouts
  short* Kh  = Qh  + (size_t)kM * kE;
  short* Vth = Kh  + (size_t)kM * kE;      // (B*H, 64, S)
  short* Ab  = Vth + (size_t)kM * kE;      // attn out bf16 (b,s,E)
  short* To  = Ab  + (size_t)kM * kE;      // 1M
  short* Wt  = To  + (size_t)kM * kR;      // 8 x 256K

  short* WtArr[8];
  for (int i = 0; i < 8; ++i) WtArr[i] = Wt + (size_t)i * (kE * kR);

  // ---- 1. weight transpose+convert ----
  PrepArgs pa;
  const int widx[8] = {3, 5, 7, 9, 11, 13, 15, 17};
  for (int i = 0; i < 8; ++i) { pa.src[i] = (const float*)d_in[widx[i]]; pa.dst[i] = WtArr[i]; }
  prep_weights<<<dim3(64, 8), dim3(256), 0, stream>>>(pa);

  // ---- 2. input convert ----
  convert_in<<<dim3((kM * kE) / (256 * 8), 3), dim3(256), 0, stream>>>(
      (const float*)d_in[0], (const float*)d_in[1], (const float*)d_in[2], Xq, Xk, Xv);

  // ---- 3. qkv lo GEMMs ----
  {
    GemmArgs ga;
    ga.A[0] = Xq; ga.A[1] = Xk; ga.A[2] = Xv;
    ga.Bt[0] = WtArr[0]; ga.Bt[1] = WtArr[2]; ga.Bt[2] = WtArr[4];
    ga.bias[0] = (const float*)d_in[4]; ga.bias[1] = (const float*)d_in[8]; ga.bias[2] = (const float*)d_in[12];
    ga.C[0] = Tq; ga.C[1] = Tk; ga.C[2] = Tv;
    ga.scale[0] = ga.scale[1] = ga.scale[2] = 1.f;
    gemm_bf16<kR, kE, 64, 64, 0><<<dim3((kM / 64) * (kR / 64), 3), dim3(256), 0, stream>>>(ga);
  }

  // ---- 4. qkv hi GEMMs -> attention layouts ----
  {
    GemmArgs ga;
    ga.A[0] = Tq; ga.A[1] = Tk; ga.A[2] = Tv;
    ga.Bt[0] = WtArr[1]; ga.Bt[1] = WtArr[3]; ga.Bt[2] = WtArr[5];
    ga.bias[0] = (const float*)d_in[6]; ga.bias[1] = (const float*)d_in[10]; ga.bias[2] = (const float*)d_in[14];
    ga.C[0] = Qh; ga.C[1] = Kh; ga.C[2] = Vth;
    // Q scale = 1/sqrt(HD) * log2(e): softmax runs in exp2/log2 domain.
    ga.scale[0] = 0.125f * 1.44269504088896340736f;
    ga.scale[1] = 1.f; ga.scale[2] = 1.f;
    gemm_bf16<kE, kR, 128, 128, 1><<<dim3((kM / 128) * (kE / 128), 3), dim3(256), 0, stream>>>(ga);
  }

  // ---- 5. attention (128 q-rows per block) ----
  attn_mfma<<<dim3(kS / 128, kB * kH), dim3(256), 0, stream>>>(Qh, Kh, Vth, Ab);

  // ---- 6. output projection ----
  {
    GemmArgs ga;
    ga.A[0] = Ab; ga.Bt[0] = WtArr[6];
    ga.bias[0] = (const float*)d_in[16];
    ga.C[0] = To; ga.scale[0] = 1.f;
    gemm_bf16<kR, kE, 64, 64, 0><<<dim3((kM / 64) * (kR / 64), 1), dim3(256), 0, stream>>>(ga);
  }
  {
    GemmArgs ga;
    ga.A[0] = To; ga.Bt[0] = WtArr[7];
    ga.bias[0] = (const float*)d_in[18];
    ga.C[0] = d_out; ga.scale[0] = 1.f;
    gemm_bf16<kE, kR, 128, 128, 2><<<dim3((kM / 128) * (kE / 128), 1), dim3(256), 0, stream>>>(ga);
  }
}